// Round 1
// baseline (102.125 us; speedup 1.0000x reference)
//
#include <hip/hip_runtime.h>
#include <math.h>

typedef __attribute__((ext_vector_type(8))) short short8;
typedef __attribute__((ext_vector_type(4))) float f32x4;

#define GLOBAL_AS __attribute__((address_space(1)))
#define LDS_AS __attribute__((address_space(3)))

__device__ inline short f2bf(float f) {
    unsigned u = __float_as_uint(f);
    u += 0x7FFFu + ((u >> 16) & 1u);   // RNE to bf16
    return (short)(u >> 16);
}

// ---------------- Kernel 1: cast x (f32 -> bf16), vectorized ----------------
__global__ __launch_bounds__(256) void cast_x_kernel(const float* __restrict__ x,
                                                     short* __restrict__ xb, long n) {
    long stride = (long)gridDim.x * blockDim.x * 8;
    for (long i = ((long)blockIdx.x * blockDim.x + threadIdx.x) * 8; i < n; i += stride) {
        float4 a = *(const float4*)(x + i);
        float4 b = *(const float4*)(x + i + 4);
        short8 o;
        o[0] = f2bf(a.x); o[1] = f2bf(a.y); o[2] = f2bf(a.z); o[3] = f2bf(a.w);
        o[4] = f2bf(b.x); o[5] = f2bf(b.y); o[6] = f2bf(b.z); o[7] = f2bf(b.w);
        *(short8*)(xb + i) = o;
    }
}

// ------ Kernel 2: cast centers (f32->bf16) + chalf[k] = 0.5*sum(c^2) in f32 ------
__global__ __launch_bounds__(256) void cast_centers_kernel(const float* __restrict__ c,
                                                           short* __restrict__ cb,
                                                           float* __restrict__ chalf, int dim) {
    int k = blockIdx.x;
    int t = threadIdx.x;
    const float* row = c + (size_t)k * dim;
    short* orow = cb + (size_t)k * dim;
    float s = 0.f;
    for (int i = t * 4; i < dim; i += blockDim.x * 4) {
        float4 v = *(const float4*)(row + i);
        s += v.x * v.x + v.y * v.y + v.z * v.z + v.w * v.w;
        short4 o;
        o.x = f2bf(v.x); o.y = f2bf(v.y); o.z = f2bf(v.z); o.w = f2bf(v.w);
        *(short4*)(orow + i) = o;
    }
#pragma unroll
    for (int off = 32; off; off >>= 1) s += __shfl_xor(s, off);
    __shared__ float red[4];
    if ((t & 63) == 0) red[t >> 6] = s;
    __syncthreads();
    if (t == 0) chalf[k] = 0.5f * (red[0] + red[1] + red[2] + red[3]);
}

// ---------------- Kernel 3: bf16 MFMA GEMM (B^T layout) + logits epilogue ----------------
// logits[b,k] = cross[b,k] - 0.5*c_sq[k]   (row-constant -0.5*x_sq cancels in log_softmax)
#define BM 128
#define BN 128
#define BK 32

__global__ __launch_bounds__(256) void gemm_logits_kernel(
    const short* __restrict__ xb,    // [M][K] bf16
    const short* __restrict__ cb,    // [N][K] bf16
    const float* __restrict__ chalf, // [N]
    float* __restrict__ out,         // [M][N]
    int M, int N, int K) {
    __shared__ short As[BM * BK];
    __shared__ short Bs[BN * BK];
    const int t = threadIdx.x;
    const int l = t & 63;
    const int w = t >> 6;
    const int wr = w >> 1, wc = w & 1;   // 2x2 wave grid, each wave does 64x64
    const int lr = l & 15;
    const int lk = (l >> 4) * 8;         // k-offset (elements) of this lane's fragment
    const int brow = blockIdx.x * BM;
    const int bcol = blockIdx.y * BN;

    f32x4 acc[4][4];
#pragma unroll
    for (int m = 0; m < 4; ++m)
#pragma unroll
        for (int n = 0; n < 4; ++n)
#pragma unroll
            for (int q = 0; q < 4; ++q) acc[m][n][q] = 0.f;

    const int row0 = t >> 2;          // 0..63: tile row of this thread's 16B chunk
    const int colb = (t & 3) * 16;    // byte offset within the 64B LDS row

    for (int kt = 0; kt < K; kt += BK) {
#pragma unroll
        for (int j = 0; j < 2; ++j) {
            const int r = row0 + j * 64;
            const char* ga = (const char*)xb + ((size_t)(brow + r) * K + kt) * 2 + colb;
            const char* gb = (const char*)cb + ((size_t)(bcol + r) * K + kt) * 2 + colb;
            __builtin_amdgcn_global_load_lds((const GLOBAL_AS int*)ga,
                                             (LDS_AS int*)((char*)As + (j * 256 + t) * 16),
                                             16, 0, 0);
            __builtin_amdgcn_global_load_lds((const GLOBAL_AS int*)gb,
                                             (LDS_AS int*)((char*)Bs + (j * 256 + t) * 16),
                                             16, 0, 0);
        }
        __syncthreads();   // compiler drains vmcnt before s_barrier

        short8 af[4], bfr[4];
#pragma unroll
        for (int m = 0; m < 4; ++m)
            af[m] = *(const short8*)&As[(wr * 64 + m * 16 + lr) * BK + lk];
#pragma unroll
        for (int n = 0; n < 4; ++n)
            bfr[n] = *(const short8*)&Bs[(wc * 64 + n * 16 + lr) * BK + lk];
#pragma unroll
        for (int m = 0; m < 4; ++m)
#pragma unroll
            for (int n = 0; n < 4; ++n)
                acc[m][n] = __builtin_amdgcn_mfma_f32_16x16x32_bf16(af[m], bfr[n], acc[m][n], 0, 0, 0);
        __syncthreads();
    }

    // Epilogue: C/D layout col = lane&15, row = (lane>>4)*4 + reg  [m89/m91]
    const int lg = l >> 4;
    float ch[4];
#pragma unroll
    for (int n = 0; n < 4; ++n) ch[n] = chalf[bcol + wc * 64 + n * 16 + lr];
#pragma unroll
    for (int m = 0; m < 4; ++m) {
        const int r0 = brow + wr * 64 + m * 16 + lg * 4;
#pragma unroll
        for (int n = 0; n < 4; ++n) {
            const int col = bcol + wc * 64 + n * 16 + lr;
#pragma unroll
            for (int q = 0; q < 4; ++q)
                out[(size_t)(r0 + q) * N + col] = acc[m][n][q] - ch[n];
        }
    }
}

// ---------------- Kernel 4: in-place row log-softmax ----------------
__global__ __launch_bounds__(256) void logsoftmax_kernel(float* __restrict__ io, int N) {
    const int row = blockIdx.x;
    const int t = threadIdx.x;
    float* p = io + (size_t)row * N;
    float4 v = *(const float4*)(p + t * 4);
    float mx = fmaxf(fmaxf(v.x, v.y), fmaxf(v.z, v.w));
#pragma unroll
    for (int off = 32; off; off >>= 1) mx = fmaxf(mx, __shfl_xor(mx, off));
    __shared__ float sm[4], se[4];
    const int w = t >> 6, l = t & 63;
    if (l == 0) sm[w] = mx;
    __syncthreads();
    mx = fmaxf(fmaxf(sm[0], sm[1]), fmaxf(sm[2], sm[3]));
    float e = __expf(v.x - mx) + __expf(v.y - mx) + __expf(v.z - mx) + __expf(v.w - mx);
#pragma unroll
    for (int off = 32; off; off >>= 1) e += __shfl_xor(e, off);
    if (l == 0) se[w] = e;
    __syncthreads();
    const float lse = mx + __logf(se[0] + se[1] + se[2] + se[3]);
    float4 o;
    o.x = v.x - lse; o.y = v.y - lse; o.z = v.z - lse; o.w = v.w - lse;
    *(float4*)(p + t * 4) = o;
}

extern "C" void kernel_launch(void* const* d_in, const int* in_sizes, int n_in,
                              void* d_out, int out_size, void* d_ws, size_t ws_size,
                              hipStream_t stream) {
    const float* x = (const float*)d_in[0];
    const float* c = (const float*)d_in[1];
    float* out = (float*)d_out;

    int dim = (int)(sqrt((double)in_sizes[1]) + 0.5);   // 1024
    int batch = in_sizes[0] / dim;                      // 16384

    // workspace layout: [centers bf16][x bf16][chalf f32]
    size_t cb_bytes = (size_t)dim * dim * 2;
    size_t xb_bytes = (size_t)batch * dim * 2;
    short* cb = (short*)d_ws;
    short* xb = (short*)((char*)d_ws + cb_bytes);
    float* chalf = (float*)((char*)d_ws + cb_bytes + xb_bytes);

    cast_x_kernel<<<4096, 256, 0, stream>>>(x, xb, (long)batch * dim);
    cast_centers_kernel<<<dim, 256, 0, stream>>>(c, cb, chalf, dim);

    dim3 grid(batch / BM, dim / BN);
    gemm_logits_kernel<<<grid, 256, 0, stream>>>(xb, cb, chalf, out, batch, dim, dim);

    logsoftmax_kernel<<<batch, 256, 0, stream>>>(out, dim);
}

// Round 2
// 83.712 us; speedup vs baseline: 1.2200x; 1.2200x over previous
//
#include <hip/hip_runtime.h>
#include <math.h>

typedef __attribute__((ext_vector_type(8))) short short8;
typedef __attribute__((ext_vector_type(4))) float f32x4;

#define GLOBAL_AS __attribute__((address_space(1)))
#define LDS_AS __attribute__((address_space(3)))

__device__ inline short f2bf(float f) {
    unsigned u = __float_as_uint(f);
    u += 0x7FFFu + ((u >> 16) & 1u);   // RNE to bf16
    return (short)(u >> 16);
}

// ---------------- Kernel 1: cast x (f32 -> bf16), vectorized ----------------
__global__ __launch_bounds__(256) void cast_x_kernel(const float* __restrict__ x,
                                                     short* __restrict__ xb, long n) {
    long stride = (long)gridDim.x * blockDim.x * 8;
    for (long i = ((long)blockIdx.x * blockDim.x + threadIdx.x) * 8; i < n; i += stride) {
        float4 a = *(const float4*)(x + i);
        float4 b = *(const float4*)(x + i + 4);
        short8 o;
        o[0] = f2bf(a.x); o[1] = f2bf(a.y); o[2] = f2bf(a.z); o[3] = f2bf(a.w);
        o[4] = f2bf(b.x); o[5] = f2bf(b.y); o[6] = f2bf(b.z); o[7] = f2bf(b.w);
        *(short8*)(xb + i) = o;
    }
}

// ------ Kernel 2: cast centers (f32->bf16) + chalf[k] = 0.5*sum(c^2) in f32 ------
__global__ __launch_bounds__(256) void cast_centers_kernel(const float* __restrict__ c,
                                                           short* __restrict__ cb,
                                                           float* __restrict__ chalf, int dim) {
    int k = blockIdx.x;
    int t = threadIdx.x;
    const float* row = c + (size_t)k * dim;
    short* orow = cb + (size_t)k * dim;
    float s = 0.f;
    for (int i = t * 4; i < dim; i += blockDim.x * 4) {
        float4 v = *(const float4*)(row + i);
        s += v.x * v.x + v.y * v.y + v.z * v.z + v.w * v.w;
        short4 o;
        o.x = f2bf(v.x); o.y = f2bf(v.y); o.z = f2bf(v.z); o.w = f2bf(v.w);
        *(short4*)(orow + i) = o;
    }
#pragma unroll
    for (int off = 32; off; off >>= 1) s += __shfl_xor(s, off);
    __shared__ float red[4];
    if ((t & 63) == 0) red[t >> 6] = s;
    __syncthreads();
    if (t == 0) chalf[k] = 0.5f * (red[0] + red[1] + red[2] + red[3]);
}

// ---------------- Kernel 3: 256x256 BK=64 MFMA GEMM, counted-vmcnt dbuf ----------------
// logits[b,k] = cross[b,k] - 0.5*c_sq[k]   (row-constant -0.5*x_sq cancels in log_softmax)
#define BM 256
#define BN 256
#define BK 64
// LDS layout: buf{0,1} of 64KB each: A[256][64] bf16 (32KB) then B[256][64] bf16 (32KB).
// Within a 128B row, 16B chunks are stored XOR-swizzled: phys_slot = logical_slot ^ (row&7).
// global_load_lds writes linearly (lane*16B), so the GLOBAL source is inverse-swizzled.

__global__ __launch_bounds__(512, 2) void gemm_logits_kernel(
    const short* __restrict__ xb,    // [M][K] bf16
    const short* __restrict__ cb,    // [N][K] bf16
    const float* __restrict__ chalf, // [N]
    float* __restrict__ out,         // [M][N]
    int M, int N, int K) {
    __shared__ char lds[131072];
    const int t = threadIdx.x;
    const int l = t & 63;
    const int w = t >> 6;
    const int wr = w >> 2, wc = w & 3;      // 2(M) x 4(N) wave grid; wave tile 128x64
    const int lr = l & 15, hi = l >> 4;

    // T1: XCD-aware swizzle. nwg = 256 (divisible by 8): each XCD gets 32 consecutive
    // swz ids = 8 M-panels x their 4 N-blocks (A-panel reuse within one L2).
    const int nnb = N / BN;                  // 4
    const int nwg = (M / BM) * nnb;          // 256
    const int bid = blockIdx.x;
    const int swz = (bid & 7) * (nwg >> 3) + (bid >> 3);
    const int brow = (swz / nnb) * BM;
    const int bcol = (swz % nnb) * BN;

    // staging geometry: 512 threads x 16B = 64 rows/round; 4 rounds per operand tile
    const int srow = t >> 3;                 // 0..63
    const int slot = t & 7;
    const int chunk = slot ^ (srow & 7);     // inverse swizzle on global source
    const size_t rowb = (size_t)K * 2;       // row stride bytes
    const char* gA = (const char*)xb + (size_t)(brow + srow) * rowb + chunk * 16;
    const char* gB = (const char*)cb + (size_t)(bcol + srow) * rowb + chunk * 16;
    const size_t rstride = rowb * 64;        // 64 rows per round
    const int ldsdst = t * 16;               // linear dest, per-wave base + lane*16

#define GLD(gp, lo) __builtin_amdgcn_global_load_lds((const GLOBAL_AS int*)(gp), \
                        (LDS_AS int*)(lds + (lo)), 16, 0, 0)
#define STAGE(curb, kt) do {                                                    \
    const size_t kofs = (size_t)(kt) * (BK * 2);                                \
    _Pragma("unroll")                                                           \
    for (int r4 = 0; r4 < 4; ++r4) {                                            \
        GLD(gA + kofs + (size_t)r4 * rstride, (curb)*65536 + r4*8192 + ldsdst); \
        GLD(gB + kofs + (size_t)r4 * rstride, (curb)*65536 + 32768 + r4*8192 + ldsdst); \
    } } while (0)

    f32x4 acc[8][4];
#pragma unroll
    for (int m = 0; m < 8; ++m)
#pragma unroll
        for (int n = 0; n < 4; ++n)
#pragma unroll
            for (int q = 0; q < 4; ++q) acc[m][n][q] = 0.f;

    const int nt = K / BK;                   // 16
    STAGE(0, 0);
    STAGE(1, 1);
    asm volatile("s_waitcnt vmcnt(8)" ::: "memory");   // tile 0 landed (8 newest still in flight)
    __builtin_amdgcn_s_barrier();

    int cur = 0;
    for (int kt = 0; kt < nt; ++kt) {
        const char* Ab = lds + cur * 65536;
        const char* Bb = Ab + 32768;
#pragma unroll
        for (int ks = 0; ks < 2; ++ks) {
            const int so = ((ks << 2) | hi) ^ (lr & 7);   // swizzled 16B slot
            short8 af[8], bf[4];
#pragma unroll
            for (int m = 0; m < 8; ++m)
                af[m] = *(const short8*)(Ab + (wr * 128 + m * 16 + lr) * 128 + so * 16);
#pragma unroll
            for (int n = 0; n < 4; ++n)
                bf[n] = *(const short8*)(Bb + (wc * 64 + n * 16 + lr) * 128 + so * 16);
            __builtin_amdgcn_s_setprio(1);
#pragma unroll
            for (int m = 0; m < 8; ++m)
#pragma unroll
                for (int n = 0; n < 4; ++n)
                    acc[m][n] = __builtin_amdgcn_mfma_f32_16x16x32_bf16(af[m], bf[n], acc[m][n], 0, 0, 0);
            __builtin_amdgcn_s_setprio(0);
        }
        if (kt == nt - 1) break;
        __builtin_amdgcn_sched_barrier(0);
        __builtin_amdgcn_s_barrier();            // all waves done reading buf[cur]
        __builtin_amdgcn_sched_barrier(0);
        if (kt + 2 < nt) {
            STAGE(cur, kt + 2);                  // overwrite freed buffer
            asm volatile("s_waitcnt vmcnt(8)" ::: "memory");  // tile kt+1 complete
        } else {
            asm volatile("s_waitcnt vmcnt(0)" ::: "memory");  // drain final tile
        }
        __builtin_amdgcn_s_barrier();            // buf[cur^1] visible to all waves
        cur ^= 1;
    }

    // Epilogue: C/D frag layout col = lane&15, row = (lane>>4)*4 + reg
    float ch[4];
#pragma unroll
    for (int n = 0; n < 4; ++n) ch[n] = chalf[bcol + wc * 64 + n * 16 + lr];
#pragma unroll
    for (int m = 0; m < 8; ++m) {
        const int r0 = brow + wr * 128 + m * 16 + hi * 4;
#pragma unroll
        for (int n = 0; n < 4; ++n) {
            const int col = bcol + wc * 64 + n * 16 + lr;
#pragma unroll
            for (int q = 0; q < 4; ++q)
                out[(size_t)(r0 + q) * N + col] = acc[m][n][q] - ch[n];
        }
    }
#undef STAGE
#undef GLD
}

// ---------------- Kernel 4: in-place row log-softmax ----------------
__global__ __launch_bounds__(256) void logsoftmax_kernel(float* __restrict__ io, int N) {
    const int row = blockIdx.x;
    const int t = threadIdx.x;
    float* p = io + (size_t)row * N;
    float4 v = *(const float4*)(p + t * 4);
    float mx = fmaxf(fmaxf(v.x, v.y), fmaxf(v.z, v.w));
#pragma unroll
    for (int off = 32; off; off >>= 1) mx = fmaxf(mx, __shfl_xor(mx, off));
    __shared__ float sm[4], se[4];
    const int w = t >> 6, l = t & 63;
    if (l == 0) sm[w] = mx;
    __syncthreads();
    mx = fmaxf(fmaxf(sm[0], sm[1]), fmaxf(sm[2], sm[3]));
    float e = __expf(v.x - mx) + __expf(v.y - mx) + __expf(v.z - mx) + __expf(v.w - mx);
#pragma unroll
    for (int off = 32; off; off >>= 1) e += __shfl_xor(e, off);
    if (l == 0) se[w] = e;
    __syncthreads();
    const float lse = mx + __logf(se[0] + se[1] + se[2] + se[3]);
    float4 o;
    o.x = v.x - lse; o.y = v.y - lse; o.z = v.z - lse; o.w = v.w - lse;
    *(float4*)(p + t * 4) = o;
}

extern "C" void kernel_launch(void* const* d_in, const int* in_sizes, int n_in,
                              void* d_out, int out_size, void* d_ws, size_t ws_size,
                              hipStream_t stream) {
    const float* x = (const float*)d_in[0];
    const float* c = (const float*)d_in[1];
    float* out = (float*)d_out;

    int dim = (int)(sqrt((double)in_sizes[1]) + 0.5);   // 1024
    int batch = in_sizes[0] / dim;                      // 16384

    // workspace layout: [centers bf16][x bf16][chalf f32]
    size_t cb_bytes = (size_t)dim * dim * 2;
    size_t xb_bytes = (size_t)batch * dim * 2;
    short* cb = (short*)d_ws;
    short* xb = (short*)((char*)d_ws + cb_bytes);
    float* chalf = (float*)((char*)d_ws + cb_bytes + xb_bytes);

    cast_x_kernel<<<4096, 256, 0, stream>>>(x, xb, (long)batch * dim);
    cast_centers_kernel<<<dim, 256, 0, stream>>>(c, cb, chalf, dim);

    int nblocks = (batch / BM) * (dim / BN);            // 256
    gemm_logits_kernel<<<nblocks, 512, 0, stream>>>(xb, cb, chalf, out, batch, dim, dim);

    logsoftmax_kernel<<<batch, 256, 0, stream>>>(out, dim);
}